// Round 7
// baseline (3630.825 us; speedup 1.0000x reference)
//
#include <hip/hip_runtime.h>

// LSTM T=256, N=128, D=H=1024, L=2.  Persistent cooperative kernel, 256 WGs x 512.
// WG (layer l, slice s) owns hidden units [8s,8s+8) => 32 gate cols, weights in LDS.
// Round-11 = round-10 resubmit (round-10 bench was an infra failure, no counters).
// Structure: x@Wih hoisted to a pre-pass (not recurrent), gx stored in consumer
// layout; l0 step loop = pure recurrence.  Audited for deadlock: prep barrier is
// all-WG under cooperative launch; gx is write-once/read-after-barrier; ws tiers
// degenerate to the round-9 (3139us, passed) path when workspace is small.
//  (1) Pre-pass: all 256 WGs compute gx[t][s] = x[t] @ Wih (l0 WGs t<128, l1 WGs
//      t>=128 with temporary l0-weight stage), stored agent-scope.  16-B-strided
//      prep flags, 256-flag poll, then l1 restages its own weights.
//  (2) l0 loop: poll -> h-phase (256 KB) -> reduce -> cell(+gx) -> store -> flag;
//      gx[t+1] prefetched right after the flag store (full step of latency cover).
//  (3) gx fp32 if ws >= NEED2+512MB, fp16 tier at +256MB, round-9 fallback else.
// Keeps: XCD partition (l0->XCD0-3), dual f0 flag lines, s-major h slots,
// compiler loads + sched_barrier(0), 16-B-strided flags, sleep(1)/sleep(2) polls.

typedef _Float16 f16;
typedef f16  v8f16 __attribute__((ext_vector_type(8)));
typedef float v4f32 __attribute__((ext_vector_type(4)));

#define TSTEPS 256
#define SLOT   131072u
static constexpr size_t HS_BANK = (size_t)258 * SLOT;   // elems per layer bank

#define SZ_W     ((size_t)2*4096*2048*2)   /* fp16 weights [l][col][k2048] */
#define SZ_B     ((size_t)2*4096*4)        /* fused bias fp32 */
#define SZ_HSEQ  ((size_t)2*258*SLOT*2)    /* h slots, 2 banks, fp16 */
#define SZ_BAR   ((size_t)16384)           /* f0a/f0b/f1/prep, 128 x 16B each */
#define SZ_XF    ((size_t)256*128*1024*2)  /* x in fp16 */
#define NEED1    (SZ_W + SZ_B + SZ_HSEQ + SZ_BAR)
#define NEED2    (NEED1 + SZ_XF)
#define SZ_GX32  ((size_t)256*128*4096*4)  /* precomputed x-gates fp32 */
#define SZ_GX16  ((size_t)256*128*4096*2)
#define NEED3_32 (NEED2 + SZ_GX32)
#define NEED3_16 (NEED2 + SZ_GX16)

__global__ void lstm_init(const float* __restrict__ x,
                          const float* __restrict__ h0,
                          const float* __restrict__ Wih, const float* __restrict__ Whh,
                          const float* __restrict__ bih, const float* __restrict__ bhh,
                          f16* __restrict__ wsW, float* __restrict__ wsB,
                          f16* __restrict__ hseq, unsigned* __restrict__ bar,
                          f16* __restrict__ xf, int do_xf)
{
    size_t tid  = (size_t)blockIdx.x * blockDim.x + threadIdx.x;
    size_t nthr = (size_t)gridDim.x * blockDim.x;
    // weights: [l][col][k], k<1024 -> W_ih, k>=1024 -> W_hh
    for (size_t i = tid; i < 16777216u; i += nthr) {
        unsigned l = (unsigned)(i >> 23), rem = (unsigned)(i & 8388607u);
        unsigned col = rem >> 11, k = rem & 2047u;
        float v = (k < 1024u) ? Wih[(size_t)l*4194304u + (size_t)col*1024u + k]
                              : Whh[(size_t)l*4194304u + (size_t)col*1024u + (k-1024u)];
        wsW[i] = (f16)v;
    }
    for (size_t i = tid; i < 8192u; i += nthr) wsB[i] = bih[i] + bhh[i];
    // initial h slots in s-major layout: (n,k) -> (k>>3)*1024 + n*8 + (k&7)
    for (size_t i = tid; i < 131072u; i += nthr) {
        unsigned n = (unsigned)(i >> 10), k = (unsigned)(i & 1023u);
        unsigned dst = ((k >> 3) << 10) + (n << 3) + (k & 7u);
        hseq[dst]           = (f16)h0[i];             // layer0 slot 0
        hseq[HS_BANK + dst] = (f16)h0[131072u + i];   // layer1 slot 0
    }
    for (size_t i = tid; i < 4096u; i += nthr) bar[i] = 0u;   // all flags
    if (do_xf) {
        for (size_t i = tid; i < 33554432u; i += nthr) xf[i] = (f16)x[i];
    }
}

__device__ __forceinline__ float sigmoid_fast(float v) { return 1.0f / (1.0f + __expf(-v)); }
__device__ __forceinline__ float tanh_fast(float v)    { return 1.0f - 2.0f / (__expf(2.0f*v) + 1.0f); }

__device__ __forceinline__ v8f16 cvt8(v4f32 lo, v4f32 hi) {
    v8f16 r;
    r[0]=(f16)lo[0]; r[1]=(f16)lo[1]; r[2]=(f16)lo[2]; r[3]=(f16)lo[3];
    r[4]=(f16)hi[0]; r[5]=(f16)hi[1]; r[6]=(f16)hi[2]; r[7]=(f16)hi[3];
    return r;
}

__device__ __forceinline__ unsigned ld_cnt(const unsigned* p) {
    return __hip_atomic_load(p, __ATOMIC_RELAXED, __HIP_MEMORY_SCOPE_AGENT);
}

#define CHUNK 8

// row-major source (xf): rows stride 1024 halves, a1 = rows +16
__device__ __forceinline__ void load_row(const f16* p, int off,
                                         v8f16 a0[CHUNK], v8f16 a1[CHUNK])
{
    #pragma unroll
    for (int i = 0; i < CHUNK; ++i) {
        a0[i] = *(const v8f16*)(p + off + 32*i);
        a1[i] = *(const v8f16*)(p + off + 16384 + 32*i);
    }
}

// s-major h slot: element (n,k) at (k>>3)*1024 + n*8 + (k&7)
__device__ __forceinline__ void load_sm(const f16* p, int off,
                                        v8f16 a0[CHUNK], v8f16 a1[CHUNK])
{
    #pragma unroll
    for (int i = 0; i < CHUNK; ++i) {
        a0[i] = *(const v8f16*)(p + off + 4096*i);
        a1[i] = *(const v8f16*)(p + off + 128 + 4096*i);   // rows +16 -> +128 halves
    }
}

// consume one 8-iteration chunk (B from LDS weights)
__device__ __forceinline__ void mfma_chunk(const v8f16 a0[CHUNK], const v8f16 a1[CHUNK],
                                           const f16 (*wl)[2056], int l15, int kq, int kbase,
                                           v4f32 acc[2][2])
{
    #pragma unroll
    for (int i = 0; i < CHUNK; ++i) {
        int k = kbase + 32*i;
        v8f16 b0 = *(const v8f16*)(&wl[l15     ][k + kq]);
        v8f16 b1 = *(const v8f16*)(&wl[16 + l15][k + kq]);
        acc[0][0] = __builtin_amdgcn_mfma_f32_16x16x32_f16(a0[i], b0, acc[0][0], 0, 0, 0);
        acc[0][1] = __builtin_amdgcn_mfma_f32_16x16x32_f16(a0[i], b1, acc[0][1], 0, 0, 0);
        acc[1][0] = __builtin_amdgcn_mfma_f32_16x16x32_f16(a1[i], b0, acc[1][0], 0, 0, 0);
        acc[1][1] = __builtin_amdgcn_mfma_f32_16x16x32_f16(a1[i], b1, acc[1][1], 0, 0, 0);
    }
}

__device__ __forceinline__ void reduce_splits(v4f32 acc[2][2], float (*gl)[36],
                                              int rb, int quad, int l15, int ks)
{
    if (ks == 0) {
        #pragma unroll
        for (int mt = 0; mt < 2; ++mt) {
            int rrow = (rb << 5) + (mt << 4) + (quad << 2);
            #pragma unroll
            for (int r = 0; r < 4; ++r) {
                gl[rrow + r][l15     ] = acc[mt][0][r];
                gl[rrow + r][16 + l15] = acc[mt][1][r];
            }
        }
    }
    __syncthreads();
    if (ks == 1) {
        #pragma unroll
        for (int mt = 0; mt < 2; ++mt) {
            int rrow = (rb << 5) + (mt << 4) + (quad << 2);
            #pragma unroll
            for (int r = 0; r < 4; ++r) {
                gl[rrow + r][l15     ] += acc[mt][0][r];
                gl[rrow + r][16 + l15] += acc[mt][1][r];
            }
        }
    }
    __syncthreads();
}

// gxv[8] adds precomputed x-gate preactivations (zeros when not used)
__device__ __forceinline__ void cell2(const float (*gl)[36], int n1, int u,
                                      const float* gxv,
                                      float bi, float bf, float bg, float bo,
                                      float& cr0, float& cr1, float& h0o, float& h1o)
{
    {
        float gi = gl[n1][u]      + gxv[0] + bi;
        float gf = gl[n1][8 + u]  + gxv[1] + bf;
        float gg = gl[n1][16 + u] + gxv[2] + bg;
        float go = gl[n1][24 + u] + gxv[3] + bo;
        float cn = sigmoid_fast(gf) * cr0 + sigmoid_fast(gi) * tanh_fast(gg);
        cr0 = cn;
        h0o = sigmoid_fast(go) * tanh_fast(cn);
    }
    {
        int n = n1 + 64;
        float gi = gl[n][u]      + gxv[4] + bi;
        float gf = gl[n][8 + u]  + gxv[5] + bf;
        float gg = gl[n][16 + u] + gxv[6] + bg;
        float go = gl[n][24 + u] + gxv[7] + bo;
        float cn = sigmoid_fast(gf) * cr1 + sigmoid_fast(gi) * tanh_fast(gg);
        cr1 = cn;
        h1o = sigmoid_fast(go) * tanh_fast(cn);
    }
}

// stage hv in LDS, then 128 threads store the WG's CONTIGUOUS 2 KB region:
// slot element (n, 8s+u) lives at s*1024 + n*8 + u
__device__ __forceinline__ void store_h_slot(f16 (*hst)[8], f16* slotbase, int s,
                                             int tid, int n1, int u,
                                             float hv0, float hv1)
{
    hst[n1     ][u] = (f16)hv0;
    hst[n1 + 64][u] = (f16)hv1;
    __syncthreads();
    if (tid < 128) {
        union { v8f16 v; unsigned long long q[2]; } c;
        c.v = *(const v8f16*)&hst[tid][0];
        unsigned long long* gp = (unsigned long long*)(slotbase + ((size_t)s << 10) + (tid << 3));
        __hip_atomic_store(gp,     c.q[0], __ATOMIC_RELAXED, __HIP_MEMORY_SCOPE_AGENT);
        __hip_atomic_store(gp + 1, c.q[1], __ATOMIC_RELAXED, __HIP_MEMORY_SCOPE_AGENT);
    }
}

__device__ __forceinline__ void stage_w(f16 (*wl)[2056], const f16* wsW,
                                        int lyr, int s, int tid)
{
    for (int idx = tid; idx < 8192; idx += 512) {
        int cc = idx >> 8;
        int k8 = (idx & 255) << 3;
        int col = ((cc >> 3) << 10) + (s << 3) + (cc & 7);
        *(v8f16*)(&wl[cc][k8]) =
            *(const v8f16*)(wsW + (((size_t)(lyr*4096 + col)) << 11) + k8);
    }
}

template<int MODE>
__device__ __forceinline__ void load_gx(const void* gxws, int t, int s, int tid, float gxv[8])
{
    size_t ge = (((size_t)t << 7) + (size_t)s) * 4096u + ((size_t)tid << 3);
    if constexpr (MODE == 2) {
        const v4f32* gp = (const v4f32*)((const float*)gxws + ge);
        v4f32 ga = gp[0], gb = gp[1];
        gxv[0]=ga[0]; gxv[1]=ga[1]; gxv[2]=ga[2]; gxv[3]=ga[3];
        gxv[4]=gb[0]; gxv[5]=gb[1]; gxv[6]=gb[2]; gxv[7]=gb[3];
    } else {
        v8f16 gv = *(const v8f16*)((const f16*)gxws + ge);
        #pragma unroll
        for (int i = 0; i < 8; ++i) gxv[i] = (float)gv[i];
    }
}

// MODE: 0 = no gx (round-9 path), 1 = fp16 gx, 2 = fp32 gx (MODE>0 requires XF16)
template<int MODE, bool XF16>
__global__ void __launch_bounds__(512)
lstm_main(const float* __restrict__ x, const f16* __restrict__ xf,
          const f16* __restrict__ wsW, const float* __restrict__ wsB,
          f16* __restrict__ hseq, const float* __restrict__ c0,
          float* __restrict__ out, unsigned* __restrict__ bar,
          void* gxws)
{
    __shared__ f16   wlds[32][2056];   // 131584 B
    __shared__ float glds[128][36];    //  18432 B (2-way max conflicts)
    __shared__ f16   hst[128][8];      //   2048 B h-store staging

    const int tid   = threadIdx.x;
    // XCD partition (dispatch heuristic: XCD = blockIdx % 8):
    // l0 -> XCDs 0-3, l1 -> XCDs 4-7; 32 WGs (= 32 CUs) of one layer per XCD.
    const int bid   = blockIdx.x;
    const int xcd   = bid & 7;
    const int layer = (xcd >> 2);
    const int s     = (bid >> 3) * 4 + (xcd & 3);   // 0..127 within layer
    const int lane  = tid & 63;
    const int wave  = tid >> 6;
    const int quad  = lane >> 4;
    const int l15   = lane & 15;
    const int rb    = wave & 3;        // rows [32rb, 32rb+32)
    const int ks    = wave >> 2;       // K-split (512-half slices per phase)

    // initial weight stage: MODE>=1 l1-WGs stage layer-0 first (for the pre-pass)
    stage_w(wlds, wsW, (MODE >= 1 && layer == 1) ? 0 : layer, s, tid);

    const int u  = tid & 7;
    const int jg = (s << 3) + u;
    const float bi = wsB[layer*4096 +        jg];
    const float bf = wsB[layer*4096 + 1024 + jg];
    const float bg = wsB[layer*4096 + 2048 + jg];
    const float bo = wsB[layer*4096 + 3072 + jg];
    const int n1 = tid >> 3;
    float cr0 = c0[((size_t)layer << 17) + ((size_t)n1 << 10) + jg];
    float cr1 = c0[((size_t)layer << 17) + ((size_t)(n1 + 64) << 10) + jg];

    __syncthreads();

    const int kq   = quad << 3;
    const int row0 = (rb << 5) + l15;
    const int kslc = ks << 9;                       // 512-half K-slice offset
    const int arow = (row0 << 10) + kslc + kq;      // row-major (xf) A offset
    const int jrow = (((kslc + kq) >> 3) << 10) + (row0 << 3);  // s-major A offset

    f16* h0b = hseq;
    f16* h1b = hseq + HS_BANK;
    unsigned* f0a  = bar;            // l0 peers poll this copy   (16-B stride)
    unsigned* f0b  = bar + 512;      // l1 polls this copy
    unsigned* f1   = bar + 1024;     // l1 own-recurrence flags
    unsigned* prep = bar + 1536;     // 256 pre-pass done flags (16-B stride, 2 banks)

    v8f16 A0[CHUNK], A1[CHUNK], C0[CHUNK], C1[CHUNK];
    float gz[8] = {0,0,0,0,0,0,0,0};

    // ---------------- pre-pass: gx[t][s] = x[t] @ Wih ----------------
    if constexpr (MODE >= 1) {
        const int tbase = (layer == 0) ? 0 : 128;
        for (int tt = 0; tt < 128; ++tt) {
            const int t = tbase + tt;
            v4f32 acc[2][2] = {};
            const f16* xp = xf + ((size_t)t << 17) + arow;
            load_row(xp, 0,   A0, A1);
            load_row(xp, 256, C0, C1);
            __builtin_amdgcn_sched_barrier(0);
            mfma_chunk(A0, A1, wlds, l15, kq, kslc,       acc);
            mfma_chunk(C0, C1, wlds, l15, kq, kslc + 256, acc);
            reduce_splits(acc, glds, rb, quad, l15, ks);
            float g0 = glds[n1][u],      g1 = glds[n1][8+u];
            float g2 = glds[n1][16+u],   g3 = glds[n1][24+u];
            float g4 = glds[n1+64][u],   g5 = glds[n1+64][8+u];
            float g6 = glds[n1+64][16+u],g7 = glds[n1+64][24+u];
            __syncthreads();   // protect glds before next iteration's write
            size_t ge = (((size_t)t << 7) + (size_t)s) * 4096u + ((size_t)tid << 3);
            if constexpr (MODE == 2) {
                union { float f[8]; unsigned long long q[4]; } gu;
                gu.f[0]=g0; gu.f[1]=g1; gu.f[2]=g2; gu.f[3]=g3;
                gu.f[4]=g4; gu.f[5]=g5; gu.f[6]=g6; gu.f[7]=g7;
                unsigned long long* gp = (unsigned long long*)((float*)gxws + ge);
                #pragma unroll
                for (int i = 0; i < 4; ++i)
                    __hip_atomic_store(gp + i, gu.q[i],
                                       __ATOMIC_RELAXED, __HIP_MEMORY_SCOPE_AGENT);
            } else {
                union { f16 h[8]; unsigned long long q[2]; } gh;
                gh.h[0]=(f16)g0; gh.h[1]=(f16)g1; gh.h[2]=(f16)g2; gh.h[3]=(f16)g3;
                gh.h[4]=(f16)g4; gh.h[5]=(f16)g5; gh.h[6]=(f16)g6; gh.h[7]=(f16)g7;
                unsigned long long* gp = (unsigned long long*)((f16*)gxws + ge);
                __hip_atomic_store(gp,     gh.q[0], __ATOMIC_RELAXED, __HIP_MEMORY_SCOPE_AGENT);
                __hip_atomic_store(gp + 1, gh.q[1], __ATOMIC_RELAXED, __HIP_MEMORY_SCOPE_AGENT);
            }
        }
        __syncthreads();   // drain gx agent stores (per-wave vmcnt)
        if (tid == 0)
            __hip_atomic_store(prep + (((layer << 7) | s) << 2), 1u,
                               __ATOMIC_RELAXED, __HIP_MEMORY_SCOPE_AGENT);
        if (tid < 256) {
            const unsigned* fp = prep + (tid << 2);
            while (ld_cnt(fp) < 1u) __builtin_amdgcn_s_sleep(2);
        }
        __syncthreads();
        if (layer == 1) stage_w(wlds, wsW, 1, s, tid);   // restore own weights
        __syncthreads();
    }

    // ---------------- recurrent loop ----------------
    if (layer == 0) {
        float gxv[8];
        if constexpr (MODE >= 1) load_gx<MODE>(gxws, 0, s, tid, gxv);

        for (int t = 0; t < TSTEPS; ++t) {
            v4f32 acc[2][2] = {};

            if constexpr (MODE == 0) {
                // in-loop x-phase (round-9 path)
                if (XF16) {
                    const f16* xp = xf + ((size_t)t << 17) + arow;
                    load_row(xp, 0,   A0, A1);
                    load_row(xp, 256, C0, C1);
                    __builtin_amdgcn_sched_barrier(0);
                    mfma_chunk(A0, A1, wlds, l15, kq, kslc,       acc);
                    mfma_chunk(C0, C1, wlds, l15, kq, kslc + 256, acc);
                } else {
                    const float* p0 = x + ((size_t)t << 17) + arow;
                    const float* p1 = p0 + (16 << 10);
                    #pragma unroll
                    for (int k = 0; k < 512; k += 32) {
                        v4f32 w0 = *(const v4f32*)(p0 + k), w1 = *(const v4f32*)(p0 + k + 4);
                        v4f32 y0 = *(const v4f32*)(p1 + k), y1 = *(const v4f32*)(p1 + k + 4);
                        v8f16 a0 = cvt8(w0, w1);
                        v8f16 a1 = cvt8(y0, y1);
                        v8f16 b0 = *(const v8f16*)(&wlds[l15     ][kslc + k + kq]);
                        v8f16 b1 = *(const v8f16*)(&wlds[16 + l15][kslc + k + kq]);
                        acc[0][0] = __builtin_amdgcn_mfma_f32_16x16x32_f16(a0, b0, acc[0][0], 0, 0, 0);
                        acc[0][1] = __builtin_amdgcn_mfma_f32_16x16x32_f16(a0, b1, acc[0][1], 0, 0, 0);
                        acc[1][0] = __builtin_amdgcn_mfma_f32_16x16x32_f16(a1, b0, acc[1][0], 0, 0, 0);
                        acc[1][1] = __builtin_amdgcn_mfma_f32_16x16x32_f16(a1, b1, acc[1][1], 0, 0, 0);
                    }
                }
            }

            // wait: all 128 l0 WGs finished step t-1
            if (t > 0) {
                if (tid < 128) {
                    const unsigned* fp = f0a + (tid << 2);
                    unsigned need = (unsigned)t;
                    while (ld_cnt(fp) < need) __builtin_amdgcn_s_sleep(1);
                }
                __syncthreads();
            }

            // dependent phase: h[t] @ Whh
            {
                const f16* hp = h0b + (size_t)t * SLOT + jrow;
                load_sm(hp, 0,     A0, A1);
                load_sm(hp, 32768, C0, C1);
                __builtin_amdgcn_sched_barrier(0);
                mfma_chunk(A0, A1, wlds, l15, kq, 1024 + kslc,       acc);
                mfma_chunk(C0, C1, wlds, l15, kq, 1024 + kslc + 256, acc);
            }

            reduce_splits(acc, glds, rb, quad, l15, ks);

            float hv0, hv1;
            cell2(glds, n1, u, (MODE >= 1) ? gxv : gz, bi, bf, bg, bo, cr0, cr1, hv0, hv1);
            store_h_slot(hst, h0b + (size_t)(t + 1) * SLOT, s, tid, n1, u, hv0, hv1);

            __syncthreads();   // drains the agent stores (vmcnt) per wave
            if (tid == 0) {
                __hip_atomic_store(f0a + (s << 2), (unsigned)(t + 1),
                                   __ATOMIC_RELAXED, __HIP_MEMORY_SCOPE_AGENT);
                __hip_atomic_store(f0b + (s << 2), (unsigned)(t + 1),
                                   __ATOMIC_RELAXED, __HIP_MEMORY_SCOPE_AGENT);
            }
            if constexpr (MODE >= 1) {
                if (t + 1 < TSTEPS) load_gx<MODE>(gxws, t + 1, s, tid, gxv);
            }
        }
    } else {
        v8f16 D0[CHUNK], D1[CHUNK];
        for (int t = 0; t < TSTEPS; ++t) {
            // wait for l0 output h0-out[t] (usually already set)
            {
                if (tid < 128) {
                    const unsigned* fp = f0b + (tid << 2);
                    unsigned need = (unsigned)(t + 1);
                    while (ld_cnt(fp) < need) __builtin_amdgcn_s_sleep(2);
                }
                __syncthreads();
            }

            v4f32 acc[2][2] = {};
            const f16* qp = h0b + (size_t)(t + 1) * SLOT + jrow;   // layer-0 out (ready)
            const f16* pp = h1b + (size_t)t * SLOT + jrow;         // own recurrence

            // issue Q loads; they fly while we poll our own recurrence flag
            load_sm(qp, 0,     A0, A1);
            load_sm(qp, 32768, C0, C1);
            __builtin_amdgcn_sched_barrier(0);

            if (t > 0) {
                if (tid < 128) {
                    const unsigned* fp = f1 + (tid << 2);
                    unsigned need = (unsigned)t;
                    while (ld_cnt(fp) < need) __builtin_amdgcn_s_sleep(2);
                }
            }
            __syncthreads();

            load_sm(pp, 0, D0, D1);                                // P0
            __builtin_amdgcn_sched_barrier(0);
            mfma_chunk(A0, A1, wlds, l15, kq, kslc,       acc);    // Q0
            load_sm(pp, 32768, A0, A1);                            // P1 (reuse A)
            __builtin_amdgcn_sched_barrier(0);
            mfma_chunk(C0, C1, wlds, l15, kq, kslc + 256, acc);    // Q1
            mfma_chunk(D0, D1, wlds, l15, kq, 1024 + kslc,       acc);   // P0
            mfma_chunk(A0, A1, wlds, l15, kq, 1024 + kslc + 256, acc);   // P1

            reduce_splits(acc, glds, rb, quad, l15, ks);

            float hv0, hv1;
            cell2(glds, n1, u, gz, bi, bf, bg, bo, cr0, cr1, hv0, hv1);
            if (t < TSTEPS - 1) {
                store_h_slot(hst, h1b + (size_t)(t + 1) * SLOT, s, tid, n1, u, hv0, hv1);
                __syncthreads();
                if (tid == 0)
                    __hip_atomic_store(f1 + (s << 2), (unsigned)(t + 1),
                                       __ATOMIC_RELAXED, __HIP_MEMORY_SCOPE_AGENT);
            } else {
                out[(n1 << 10) + jg] = hv0;
                out[((n1 + 64) << 10) + jg] = hv1;
            }
        }
    }
}

extern "C" void kernel_launch(void* const* d_in, const int* in_sizes, int n_in,
                              void* d_out, int out_size, void* d_ws, size_t ws_size,
                              hipStream_t stream) {
    const float* x   = (const float*)d_in[0];
    const float* h0  = (const float*)d_in[1];
    const float* c0  = (const float*)d_in[2];
    const float* Wih = (const float*)d_in[3];
    const float* Whh = (const float*)d_in[4];
    const float* bih = (const float*)d_in[5];
    const float* bhh = (const float*)d_in[6];
    float* out = (float*)d_out;

    char* ws = (char*)d_ws;
    const bool xf16 = (ws_size >= NEED2);

    f16*      wsW  = (f16*)ws;
    float*    wsB  = (float*)(ws + SZ_W);
    f16*      hseq = (f16*)(ws + SZ_W + SZ_B);
    unsigned* bar  = (unsigned*)(ws + SZ_W + SZ_B + SZ_HSEQ);
    f16*      xf   = (f16*)(ws + NEED1);
    void*     gxws = (void*)(ws + NEED2);
    int do_xf = xf16 ? 1 : 0;

    lstm_init<<<2048, 256, 0, stream>>>(x, h0, Wih, Whh, bih, bhh,
                                        wsW, wsB, hseq, bar, xf, do_xf);

    void* kargs[] = { (void*)&x, (void*)&xf, (void*)&wsW, (void*)&wsB,
                      (void*)&hseq, (void*)&c0, (void*)&out, (void*)&bar,
                      (void*)&gxws };
    if (ws_size >= NEED3_32) {
        hipLaunchCooperativeKernel((void*)&lstm_main<2, true>, dim3(256), dim3(512), kargs, 0, stream);
    } else if (ws_size >= NEED3_16) {
        hipLaunchCooperativeKernel((void*)&lstm_main<1, true>, dim3(256), dim3(512), kargs, 0, stream);
    } else if (xf16) {
        hipLaunchCooperativeKernel((void*)&lstm_main<0, true>, dim3(256), dim3(512), kargs, 0, stream);
    } else {
        hipLaunchCooperativeKernel((void*)&lstm_main<0, false>, dim3(256), dim3(512), kargs, 0, stream);
    }
}